// Round 4
// baseline (205.416 us; speedup 1.0000x reference)
//
#include <hip/hip_runtime.h>
#include <math.h>

#define NB     8
#define BATCH  64
#define FEAT   512
#define WHALF  513                 // W/2 + 1
#define PIX    (1024 * 513)        // 525312
#define MAX_R  0x1.6A09E6p-1f      // sqrtf(0.5f) == reference radius.max()

typedef float vfloat4 __attribute__((ext_vector_type(4)));

// ---------------------------------------------------------------------------
// Band classification, bit-exact vs the numpy reference (verified r1/r3):
//   r2 = u*u + v*v is EXACT in f32 (k^2 + l^2 <= 2^19 fits the mantissa),
//   sqrtf is correctly rounded, boundaries use the identical f32 expression
//   max_r * (i/8).  Returns 8 for the single r == max_r pixel (-> weight 0).
// ---------------------------------------------------------------------------
__device__ __forceinline__ int band_of(int p) {
    const int h  = p / WHALF;
    const int wp = p - h * WHALF;
    const float u = (float)wp * 0.0009765625f;                  // wp / 1024, exact
    const int hv  = (h >= 512) ? (h - 1024) : h;                // fftfreq numerator
    const float v = (float)hv * 0.0009765625f;                  // exact
    const float r = sqrtf(fmaf(u, u, v * v));                   // r2 exact -> r CR

    int j = (int)(r * (8.0f / MAX_R));                          // estimate
    if (j > 8) j = 8;
    const float lo = MAX_R * ((float)j * 0.125f);               // == ref lower[j]
    if (r < lo) {
        --j;
    } else if (j < 8) {
        const float hi = MAX_R * ((float)(j + 1) * 0.125f);     // == ref upper[j]
        if (r >= hi) ++j;
    }
    return j;                                                   // 0..7, or 8 = none
}

// ---------------------------------------------------------------------------
// Single fused kernel. Block = (pixel-chunk of 1024, batch-group of 8).
// Phase 1: softmax weights for THIS block's 8 batches (redundant across the
//          513 chunk-blocks; 128 FMA/thread, operands are 32 KB and stay
//          L1/L2-resident -> ~0.3 us, hidden under neighboring blocks' stores).
// Phase 2: inline band classification (4 pixels/thread) + 8 nontemporal
//          float4 stores (one per batch). LDS table reads are same-address
//          broadcasts (band locally constant) -> conflict-free.
// ---------------------------------------------------------------------------
__global__ void __launch_bounds__(256)
fused_kernel(const float* __restrict__ ff,
             const float* __restrict__ w,
             const float* __restrict__ bias,
             float* __restrict__ out) {
    const int t     = threadIdx.x;
    const int chunk = blockIdx.x >> 3;           // 0..512
    const int bg    = blockIdx.x & 7;            // batch-group of 8

    __shared__ float red[4][64];
    __shared__ float sbw[NB * 9];                // 8 batches x {8 weights + 0-pad}

    // ---- phase 1: 64 dot-products (8 batches x 8 bands), k split 4-way ----
    {
        const int pair = t & 63;                 // bl*8 + n
        const int q    = t >> 6;                 // k-quarter (wave id)
        const int bl   = pair >> 3, n = pair & 7;
        const float* fr = ff + (size_t)(bg * 8 + bl) * FEAT + q * 128;
        const float* wr = w  + (size_t)n * FEAT + q * 128;
        float acc = 0.0f;
#pragma unroll
        for (int k = 0; k < 128; k += 4) {
            const float4 a = *reinterpret_cast<const float4*>(fr + k);
            const float4 c = *reinterpret_cast<const float4*>(wr + k);
            acc += a.x * c.x + a.y * c.y + a.z * c.z + a.w * c.w;
        }
        red[q][pair] = acc;
    }
    __syncthreads();

    if (t < 64) {                                // wave 0: softmax per batch
        const int bl = t >> 3, n = t & 7;
        float logit = red[0][t] + red[1][t] + red[2][t] + red[3][t] + bias[n];
        float m = logit;
#pragma unroll
        for (int s = 1; s < 8; s <<= 1) m = fmaxf(m, __shfl_xor(m, s));
        const float e = expf(logit - m);
        float sum = e;
#pragma unroll
        for (int s = 1; s < 8; s <<= 1) sum += __shfl_xor(sum, s);
        sbw[bl * 9 + n] = e / sum;
        if (n == 0) sbw[bl * 9 + 8] = 0.0f;      // band 8 (r == max_r) -> 0
    }
    __syncthreads();

    // ---- phase 2: classify 4 pixels, store 8 batch planes ----
    const int p  = chunk * 1024 + t * 4;
    const int j0 = band_of(p + 0);
    const int j1 = band_of(p + 1);
    const int j2 = band_of(p + 2);
    const int j3 = band_of(p + 3);

    float* o = out + (size_t)(bg * 8) * PIX + p;
#pragma unroll
    for (int i = 0; i < 8; ++i) {
        const float* row = sbw + i * 9;
        vfloat4 v;
        v.x = row[j0];
        v.y = row[j1];
        v.z = row[j2];
        v.w = row[j3];
        __builtin_nontemporal_store(v, reinterpret_cast<vfloat4*>(o));
        o += PIX;
    }
}

extern "C" void kernel_launch(void* const* d_in, const int* in_sizes, int n_in,
                              void* d_out, int out_size, void* d_ws, size_t ws_size,
                              hipStream_t stream) {
    const float* ff   = (const float*)d_in[0];   // [64, 512]
    const float* w    = (const float*)d_in[1];   // [8, 512]
    const float* bias = (const float*)d_in[2];   // [8]
    float* out = (float*)d_out;                  // [64, 1, 1024, 513] f32

    (void)d_ws; (void)ws_size;                   // no scratch needed
    fused_kernel<<<513 * 8, 256, 0, stream>>>(ff, w, bias, out);
}

// Round 5
// 149.937 us; speedup vs baseline: 1.3700x; 1.3700x over previous
//
#include <hip/hip_runtime.h>
#include <math.h>

#define NB     8
#define BATCH  64
#define FEAT   512
#define WHALF  513                 // W/2 + 1
#define PIX    (1024 * 513)        // 525312
#define MAX_R  0x1.6A09E6p-1f      // sqrtf(0.5f) == reference radius.max()

typedef float vfloat4 __attribute__((ext_vector_type(4)));

// ---------------------------------------------------------------------------
// Band classification, bit-exact vs the numpy reference (verified r1/r3/r4):
//   r2 = u*u + v*v is EXACT in f32 (k^2 + l^2 <= 2^19 fits the mantissa),
//   sqrtf is correctly rounded, boundaries use the identical f32 expression
//   max_r * (i/8).  Returns 8 for the single r == max_r pixel (-> weight 0).
// ---------------------------------------------------------------------------
__device__ __forceinline__ int band_of(int p) {
    const int h  = p / WHALF;
    const int wp = p - h * WHALF;
    const float u = (float)wp * 0.0009765625f;                  // wp / 1024, exact
    const int hv  = (h >= 512) ? (h - 1024) : h;                // fftfreq numerator
    const float v = (float)hv * 0.0009765625f;                  // exact
    const float r = sqrtf(fmaf(u, u, v * v));                   // r2 exact -> r CR

    int j = (int)(r * (8.0f / MAX_R));                          // estimate
    if (j > 8) j = 8;
    const float lo = MAX_R * ((float)j * 0.125f);               // == ref lower[j]
    if (r < lo) {
        --j;
    } else if (j < 8) {
        const float hi = MAX_R * ((float)(j + 1) * 0.125f);     // == ref upper[j]
        if (r >= hi) ++j;
    }
    return j;                                                   // 0..7, or 8 = none
}

// ---------------------------------------------------------------------------
// K1: bw[b][n] = softmax(ff[b] @ w.T + bias) -> ws (computed ONCE; r4 showed
// recomputing this per writer-block costs ~1 GB of L2 reads and 3x the time).
// ---------------------------------------------------------------------------
__global__ void bw_kernel(const float* __restrict__ ff,
                          const float* __restrict__ w,
                          const float* __restrict__ bias,
                          float* __restrict__ bw) {
    const int b = blockIdx.x;      // one block per batch row
    const int t = threadIdx.x;     // 256 threads

    float part[NB];
#pragma unroll
    for (int n = 0; n < NB; ++n) part[n] = 0.0f;

    for (int k = t; k < FEAT; k += 256) {
        const float f = ff[b * FEAT + k];
#pragma unroll
        for (int n = 0; n < NB; ++n) part[n] += f * w[n * FEAT + k];
    }

#pragma unroll
    for (int n = 0; n < NB; ++n) {
#pragma unroll
        for (int off = 32; off > 0; off >>= 1)
            part[n] += __shfl_down(part[n], off);
    }

    __shared__ float red[4][NB];
    const int wave = t >> 6, lane = t & 63;
    if (lane == 0) {
#pragma unroll
        for (int n = 0; n < NB; ++n) red[wave][n] = part[n];
    }
    __syncthreads();

    if (t == 0) {
        float logit[NB], m = -1e30f;
#pragma unroll
        for (int n = 0; n < NB; ++n) {
            logit[n] = red[0][n] + red[1][n] + red[2][n] + red[3][n] + bias[n];
            m = fmaxf(m, logit[n]);
        }
        float s = 0.0f;
#pragma unroll
        for (int n = 0; n < NB; ++n) { logit[n] = expf(logit[n] - m); s += logit[n]; }
        const float inv = 1.0f / s;
#pragma unroll
        for (int n = 0; n < NB; ++n) bw[b * NB + n] = logit[n] * inv;
    }
}

// ---------------------------------------------------------------------------
// K2: block = (pixel-chunk of 1024, batch-group of 8). Reads only its 8
// batches' weights (64 floats) from ws into a 72-entry padded LDS table,
// classifies 4 pixels inline (~120 VALU ops, proven cheap in r4: VALUBusy
// 12.9%), then 8 nontemporal float4 stores (one per batch plane). LDS reads
// are same-address broadcasts (band locally constant) -> conflict-free.
// ---------------------------------------------------------------------------
__global__ void __launch_bounds__(256)
out_kernel(const float* __restrict__ bw, float* __restrict__ out) {
    const int t     = threadIdx.x;
    const int chunk = blockIdx.x >> 3;           // 0..512
    const int bg    = blockIdx.x & 7;            // batch-group of 8

    __shared__ float sbw[8 * 9];                 // 8 batches x {8 weights + 0-pad}
    if (t < 72) {
        const int bl = t / 9, j = t - bl * 9;
        sbw[t] = (j < NB) ? bw[(bg * 8 + bl) * NB + j] : 0.0f;
    }
    __syncthreads();

    const int p  = chunk * 1024 + t * 4;
    const int j0 = band_of(p + 0);
    const int j1 = band_of(p + 1);
    const int j2 = band_of(p + 2);
    const int j3 = band_of(p + 3);

    float* o = out + (size_t)(bg * 8) * PIX + p;
#pragma unroll
    for (int i = 0; i < 8; ++i) {
        const float* row = sbw + i * 9;
        vfloat4 v;
        v.x = row[j0];
        v.y = row[j1];
        v.z = row[j2];
        v.w = row[j3];
        __builtin_nontemporal_store(v, reinterpret_cast<vfloat4*>(o));
        o += PIX;
    }
}

extern "C" void kernel_launch(void* const* d_in, const int* in_sizes, int n_in,
                              void* d_out, int out_size, void* d_ws, size_t ws_size,
                              hipStream_t stream) {
    const float* ff   = (const float*)d_in[0];   // [64, 512]
    const float* w    = (const float*)d_in[1];   // [8, 512]
    const float* bias = (const float*)d_in[2];   // [8]
    float* out = (float*)d_out;                  // [64, 1, 1024, 513] f32

    float* bw = (float*)d_ws;                    // 2048 B of the workspace

    bw_kernel<<<BATCH, 256, 0, stream>>>(ff, w, bias, bw);
    out_kernel<<<513 * 8, 256, 0, stream>>>(bw, out);
}